// Round 12
// baseline (1828.343 us; speedup 1.0000x reference)
//
#include <hip/hip_runtime.h>
#include <hip/hip_fp16.h>
#include <math.h>

#define N_NODES 100000
#define N_EDGES 3200000
#define H 32
#define SCAN_BLOCKS ((N_NODES + 255) / 256)   // 391
#define HSTRIDE 34                            // fp16 tile stride (conflict-free)

typedef float f32x4 __attribute__((ext_vector_type(4)));
typedef float f32x2 __attribute__((ext_vector_type(2)));

__device__ __forceinline__ float lrelu(float v) { return v > 0.0f ? v : 0.01f * v; }

// ---- packed slot record: e (22b) | dst (17b) | src (17b) ----
__device__ __forceinline__ uint2 pack_eds(int e, int dst, int src) {
    uint2 r;
    r.x = (unsigned)e | ((unsigned)(dst & 0x3FF) << 22);
    r.y = ((unsigned)dst >> 10) | ((unsigned)src << 7);
    return r;
}
__device__ __forceinline__ int unpack_e(uint2 p)   { return (int)(p.x & 0x3FFFFF); }
__device__ __forceinline__ int unpack_dst(uint2 p) { return (int)((p.x >> 22) | ((p.y & 0x7F) << 10)); }
__device__ __forceinline__ int unpack_src(uint2 p) { return (int)(p.y >> 7); }

__device__ __forceinline__ void matvec32(const float* __restrict__ in,
                                         const float* __restrict__ W,
                                         const float* __restrict__ bias,
                                         float* __restrict__ out) {
#pragma unroll
    for (int o = 0; o < H; ++o) out[o] = bias[o];
#pragma unroll
    for (int k = 0; k < H; ++k) {
        float v = in[k];
#pragma unroll
        for (int o = 0; o < H; ++o) out[o] = fmaf(v, W[k * H + o], out[o]);
    }
}

__device__ __forceinline__ void matvec32_acc(const float* __restrict__ in,
                                             const float* __restrict__ W,
                                             float* __restrict__ out) {
#pragma unroll
    for (int k = 0; k < H; ++k) {
        float v = in[k];
#pragma unroll
        for (int o = 0; o < H; ++o) out[o] = fmaf(v, W[k * H + o], out[o]);
    }
}

__device__ __forceinline__ void load_row32(const float* __restrict__ p, float* __restrict__ r) {
    const f32x4* p4 = reinterpret_cast<const f32x4*>(p);
#pragma unroll
    for (int q = 0; q < 8; ++q) {
        f32x4 v = p4[q];
        r[4 * q + 0] = v.x; r[4 * q + 1] = v.y; r[4 * q + 2] = v.z; r[4 * q + 3] = v.w;
    }
}

// non-temporal row load (read-once streams; keep L3 for hs)
__device__ __forceinline__ void load_row32_nt(const float* __restrict__ p, float* __restrict__ r) {
    const f32x4* p4 = reinterpret_cast<const f32x4*>(p);
#pragma unroll
    for (int q = 0; q < 8; ++q) {
        f32x4 v = __builtin_nontemporal_load(p4 + q);
        r[4 * q + 0] = v.x; r[4 * q + 1] = v.y; r[4 * q + 2] = v.z; r[4 * q + 3] = v.w;
    }
}

// non-temporal row store (write-only outputs)
__device__ __forceinline__ void store_row32_nt(float* __restrict__ p, const float* __restrict__ r) {
    f32x4* p4 = reinterpret_cast<f32x4*>(p);
#pragma unroll
    for (int q = 0; q < 8; ++q) {
        f32x4 v;
        v.x = r[4 * q + 0]; v.y = r[4 * q + 1]; v.z = r[4 * q + 2]; v.w = r[4 * q + 3];
        __builtin_nontemporal_store(v, p4 + q);
    }
}

__device__ __forceinline__ void load_row32_h(const __half2* __restrict__ p, float* __restrict__ r) {
#pragma unroll
    for (int q = 0; q < 16; ++q) {
        float2 f = __half22float2(p[q]);
        r[2 * q + 0] = f.x; r[2 * q + 1] = f.y;
    }
}

__device__ __forceinline__ void store_row32_h(__half2* __restrict__ p, const float* __restrict__ r) {
#pragma unroll
    for (int q = 0; q < 16; ++q) p[q] = __floats2half2_rn(r[2 * q], r[2 * q + 1]);
}

__device__ __forceinline__ void hnode_row(const float* __restrict__ x, int i,
                                          const float* __restrict__ W_in,
                                          const float* __restrict__ b_in,
                                          float* __restrict__ r) {
    float x0 = x[(size_t)i * 3 + 0], x1 = x[(size_t)i * 3 + 1], x2 = x[(size_t)i * 3 + 2];
#pragma unroll
    for (int o = 0; o < H; ++o)
        r[o] = fmaf(x2, W_in[2 * H + o], fmaf(x1, W_in[1 * H + o], fmaf(x0, W_in[0 * H + o], b_in[o])));
}

// per-group segment scan over 32 staged fp16 LDS slots; lane owns one channel.
__device__ __forceinline__ void seg_scan32_h(const __half* __restrict__ tile,
                                             const int* __restrict__ nid,
                                             int base, int lane,
                                             float* __restrict__ out) {
    int cur = nid[base];
    float acc = __half2float(tile[base * HSTRIDE + lane]);
    bool started = false;
#pragma unroll 4
    for (int j = 1; j < 32; ++j) {
        int n = nid[base + j];
        float v = __half2float(tile[(base + j) * HSTRIDE + lane]);
        if (n != cur) {
            if (started) out[(size_t)cur * H + lane] = acc;
            else atomicAdd(out + (size_t)cur * H + lane, acc);
            started = true;
            cur = n;
            acc = v;
        } else {
            acc += v;
        }
    }
    atomicAdd(out + (size_t)cur * H + lane, acc);
}

__device__ __forceinline__ void staged_segsum(const float* __restrict__ m,
                                              int dst, int tid,
                                              __half* __restrict__ tile,
                                              int* __restrict__ nid,
                                              float* __restrict__ out) {
    nid[tid] = dst;
    __half2* row = reinterpret_cast<__half2*>(tile + tid * HSTRIDE);
#pragma unroll
    for (int q = 0; q < 16; ++q) row[q] = __floats2half2_rn(m[2 * q], m[2 * q + 1]);
    __syncthreads();
    seg_scan32_h(tile, nid, tid & ~31, tid & 31, out);
}

// ---------------- fold ----------------
__global__ __launch_bounds__(1024) void fold_kernel(const float* __restrict__ We,
                                                    const float* __restrict__ be,
                                                    const float* __restrict__ WN1,
                                                    const float* __restrict__ bN1,
                                                    float* __restrict__ W2,
                                                    float* __restrict__ Wfold,
                                                    float* __restrict__ c1,
                                                    float* __restrict__ c0) {
    int t = threadIdx.x;
    int k = t >> 5, o = t & 31;
    float s2 = 0.0f, sf = 0.0f;
#pragma unroll
    for (int j = 0; j < H; ++j) {
        float w = We[k * H + j];
        s2 = fmaf(w, WN1[j * H + o], s2);
        sf = fmaf(w, WN1[(H + j) * H + o], sf);
    }
    W2[t] = s2;
    Wfold[t] = sf;
    if (k == 0) {
        float a = 0.0f, b = 0.0f;
#pragma unroll
        for (int j = 0; j < H; ++j) {
            a = fmaf(be[j], WN1[j * H + o], a);
            b = fmaf(be[j], WN1[(H + j) * H + o], b);
        }
        c1[o] = a;
        c0[o] = bN1[o] + b;
    }
}

// ---------------- utility ----------------
__global__ __launch_bounds__(256) void zero_int_kernel(int* __restrict__ p, int n) {
    int i = blockIdx.x * blockDim.x + threadIdx.x;
    if (i < n) p[i] = 0;
}

// ---------------- CSR build ----------------
__global__ __launch_bounds__(256) void hist_kernel(const int* __restrict__ eidx, int* __restrict__ cnt) {
    int e = blockIdx.x * blockDim.x + threadIdx.x;
    if (e >= N_EDGES) return;
    atomicAdd(&cnt[eidx[(size_t)N_EDGES + e]], 1);
}

__global__ __launch_bounds__(256) void scan_block_kernel(const int* __restrict__ cnt,
                                                         int* __restrict__ ptr,
                                                         int* __restrict__ bsum) {
    __shared__ int sm[256];
    int idx = blockIdx.x * 256 + threadIdx.x;
    int v = (idx < N_NODES) ? cnt[idx] : 0;
    sm[threadIdx.x] = v;
    __syncthreads();
    for (int off = 1; off < 256; off <<= 1) {
        int t = (threadIdx.x >= off) ? sm[threadIdx.x - off] : 0;
        __syncthreads();
        sm[threadIdx.x] += t;
        __syncthreads();
    }
    if (idx < N_NODES) ptr[idx] = sm[threadIdx.x] - v;
    if (threadIdx.x == 255) bsum[blockIdx.x] = sm[255];
}

__global__ __launch_bounds__(512) void scan_bsum_kernel(int* __restrict__ bsum, int nb) {
    __shared__ int sm[512];
    int v = (threadIdx.x < nb) ? bsum[threadIdx.x] : 0;
    sm[threadIdx.x] = v;
    __syncthreads();
    for (int off = 1; off < 512; off <<= 1) {
        int t = (threadIdx.x >= off) ? sm[threadIdx.x - off] : 0;
        __syncthreads();
        sm[threadIdx.x] += t;
        __syncthreads();
    }
    if (threadIdx.x < nb) bsum[threadIdx.x] = sm[threadIdx.x] - v;
}

// add block offsets; init fill=ptr; zero raw (pre-seg_stage); set ptr[N]
__global__ __launch_bounds__(256) void scan_fix_kernel(int* __restrict__ ptr,
                                                       int* __restrict__ fill,
                                                       const int* __restrict__ bsum,
                                                       float* __restrict__ raw) {
    int idx = blockIdx.x * 256 + threadIdx.x;
    if (idx < N_NODES) {
        int p = ptr[idx] + bsum[blockIdx.x];
        ptr[idx] = p;
        fill[idx] = p;
        f32x4 z = (f32x4)(0.0f);
        f32x4* r4 = reinterpret_cast<f32x4*>(raw + (size_t)idx * H);
#pragma unroll
        for (int q = 0; q < 8; ++q) r4[q] = z;
    }
    if (idx == 0) ptr[N_NODES] = N_EDGES;
}

// scatter: materialize slot-sorted fp16 h_msg + packed {e,dst,src}
__global__ __launch_bounds__(256) void scatter_big_kernel(const int* __restrict__ eidx,
                                                          const float* __restrict__ h_msg,
                                                          int* __restrict__ fill,
                                                          uint2* __restrict__ slotmap,
                                                          __half* __restrict__ hs) {
    int e = blockIdx.x * blockDim.x + threadIdx.x;
    if (e >= N_EDGES) return;
    int src = eidx[e];
    int dst = eidx[(size_t)N_EDGES + e];
    float m[H];
    load_row32_nt(h_msg + (size_t)e * H, m);       // read-once stream: keep out of L3
    int pos = atomicAdd(&fill[dst], 1);
    slotmap[pos] = pack_eds(e, dst, src);          // 8B random write
    store_row32_h(reinterpret_cast<__half2*>(hs + (size_t)pos * H), m); // 64B, want L3
}

__global__ __launch_bounds__(256) void seg_stage_big_kernel(const __half* __restrict__ hs,
                                                            const uint2* __restrict__ slotmap,
                                                            float* __restrict__ out) {
    __shared__ __half tile[256 * HSTRIDE];
    __shared__ int nid[256];
    int tid = threadIdx.x;
    int slot = blockIdx.x * 256 + tid;
    nid[tid] = unpack_dst(slotmap[slot]);
    const __half2* row = reinterpret_cast<const __half2*>(hs + (size_t)slot * H);  // sequential, L3-hot
    __half2* trow = reinterpret_cast<__half2*>(tile + tid * HSTRIDE);
#pragma unroll
    for (int q = 0; q < 16; ++q) trow[q] = row[q];
    __syncthreads();
    seg_scan32_h(tile, nid, tid & ~31, tid & 31, out);
}

// ---------------- per-node: pre1 + nn MLP -> fp16 pernode[n][64]; re-zeros raw ----------------
__global__ __launch_bounds__(256) void pernode_kernel(const float* __restrict__ x,
                                                      float* __restrict__ raw,
                                                      const int* __restrict__ ptr,
                                                      const float* __restrict__ W_in,
                                                      const float* __restrict__ b_in,
                                                      const float* __restrict__ Wn1,
                                                      const float* __restrict__ bn1,
                                                      const float* __restrict__ Wn2,
                                                      const float* __restrict__ bn2,
                                                      const float* __restrict__ W2,
                                                      const float* __restrict__ c1,
                                                      const float* __restrict__ c0,
                                                      __half* __restrict__ pernode) {
    int i = blockIdx.x * blockDim.x + threadIdx.x;
    if (i >= N_NODES) return;
    float s[H], p1[H];
    __half2* row = reinterpret_cast<__half2*>(pernode + (size_t)i * 64);
    load_row32(raw + (size_t)i * H, s);
    // re-zero raw for the aggr_out accumulation in edge_fused (same slot reuse)
    {
        f32x4 z = (f32x4)(0.0f);
        f32x4* r4 = reinterpret_cast<f32x4*>(raw + (size_t)i * H);
#pragma unroll
        for (int q = 0; q < 8; ++q) r4[q] = z;
    }
    float deg = (float)(ptr[i + 1] - ptr[i]);
#pragma unroll
    for (int o = 0; o < H; ++o) p1[o] = fmaf(deg, c1[o], c0[o]);
    matvec32_acc(s, W2, p1);
    store_row32_h(row, p1);
    hnode_row(x, i, W_in, b_in, s);
    matvec32(s, Wn1, bn1, p1);
#pragma unroll
    for (int o = 0; o < H; ++o) p1[o] = lrelu(p1[o]);
    matvec32(p1, Wn2, bn2, s);
#pragma unroll
    for (int o = 0; o < H; ++o) s[o] = lrelu(s[o]);
    store_row32_h(row + 16, s);
}

// ---------------- fused pass2 ----------------
__global__ __launch_bounds__(256) void edge_fused_big_kernel(
    const __half* __restrict__ hs, const uint2* __restrict__ slotmap,
    const __half* __restrict__ pernode,
    const float* __restrict__ Wfold,
    const float* __restrict__ WN2, const float* __restrict__ bN2,
    const float* __restrict__ Wd, const float* __restrict__ bd,
    float* __restrict__ out_hmsg, float* __restrict__ out_ymsg,
    float* __restrict__ aggr_out) {
    __shared__ __half tile[256 * HSTRIDE];
    __shared__ int nid[256];
    int tid = threadIdx.x;
    int slot = blockIdx.x * 256 + tid;
    uint2 sm = slotmap[slot];                       // sequential 8B
    int e = unpack_e(sm), dst = unpack_dst(sm), src = unpack_src(sm);

    float m[H], t[H], u[H];
    const __half2* pn = reinterpret_cast<const __half2*>(pernode + (size_t)src * 64);

    load_row32_h(reinterpret_cast<const __half2*>(hs + (size_t)slot * H), m);  // sequential, L3-hot
    load_row32_h(pn, t);                            // remaining random gather
    matvec32_acc(m, Wfold, t);
#pragma unroll
    for (int o = 0; o < H; ++o) t[o] = lrelu(t[o]);

    matvec32(t, WN2, bN2, u);

    load_row32_h(pn + 16, t);
#pragma unroll
    for (int o = 0; o < H; ++o) m[o] = t[o] + lrelu(u[o]);

    store_row32_nt(out_hmsg + (size_t)e * H, m);    // write-only: bypass L3

    float z0 = bd[0], z1 = bd[1];
#pragma unroll
    for (int k = 0; k < H; ++k) {
        z0 = fmaf(m[k], Wd[k * 2 + 0], z0);
        z1 = fmaf(m[k], Wd[k * 2 + 1], z1);
    }
    float zm = fmaxf(z0, z1);
    float e0 = __expf(z0 - zm), e1 = __expf(z1 - zm);
    float inv = 1.0f / (e0 + e1);
    f32x2 y; y.x = e0 * inv; y.y = e1 * inv;
    __builtin_nontemporal_store(y, reinterpret_cast<f32x2*>(out_ymsg + (size_t)e * 2));

    staged_segsum(m, dst, tid, tile, nid, aggr_out);
}

// ---------------- node update + beliefs ----------------
__global__ __launch_bounds__(256) void node_update_kernel(
    const float* __restrict__ x, const float* __restrict__ aggr_out,
    const float* __restrict__ W_in, const float* __restrict__ b_in,
    const float* __restrict__ WU, const float* __restrict__ bU,
    const float* __restrict__ Wb, const float* __restrict__ bb,
    float* __restrict__ out_beliefs) {
    int i = blockIdx.x * blockDim.x + threadIdx.x;
    if (i >= N_NODES) return;
    float a[H], t[H];
    hnode_row(x, i, W_in, b_in, a);
    matvec32(a, WU, bU, t);
    load_row32(aggr_out + (size_t)i * H, a);
    matvec32_acc(a, WU + H * H, t);
#pragma unroll
    for (int o = 0; o < H; ++o) t[o] = lrelu(t[o]);

    if (x[(size_t)i * 3] == 1.0f) {
        float z0 = bb[0], z1 = bb[1];
#pragma unroll
        for (int k = 0; k < H; ++k) {
            z0 = fmaf(t[k], Wb[k * 2 + 0], z0);
            z1 = fmaf(t[k], Wb[k * 2 + 1], z1);
        }
        float zm = fmaxf(z0, z1);
        float e0 = __expf(z0 - zm), e1 = __expf(z1 - zm);
        float inv = 1.0f / (e0 + e1);
        f32x2 y; y.x = e0 * inv; y.y = e1 * inv;
        __builtin_nontemporal_store(y, reinterpret_cast<f32x2*>(out_beliefs + (size_t)i * 2));
    }
}

extern "C" void kernel_launch(void* const* d_in, const int* in_sizes, int n_in,
                              void* d_out, int out_size, void* d_ws, size_t ws_size,
                              hipStream_t stream) {
    const float* x     = (const float*)d_in[0];
    const int*   eidx  = (const int*)d_in[1];
    const float* h_msg = (const float*)d_in[2];
    const float* W_in = (const float*)d_in[3];  const float* b_in = (const float*)d_in[4];
    const float* We   = (const float*)d_in[5];  const float* be   = (const float*)d_in[6];
    const float* Wn1  = (const float*)d_in[7];  const float* bn1  = (const float*)d_in[8];
    const float* Wn2  = (const float*)d_in[9];  const float* bn2  = (const float*)d_in[10];
    const float* WN1  = (const float*)d_in[11]; const float* bN1  = (const float*)d_in[12];
    const float* WN2  = (const float*)d_in[13]; const float* bN2  = (const float*)d_in[14];
    const float* WU   = (const float*)d_in[15]; const float* bU   = (const float*)d_in[16];
    const float* Wd   = (const float*)d_in[17]; const float* bd   = (const float*)d_in[18];
    const float* Wb   = (const float*)d_in[19]; const float* bb   = (const float*)d_in[20];

    float* out         = (float*)d_out;
    float* out_hmsg    = out;
    float* out_ymsg    = out + (size_t)N_EDGES * H;
    float* out_beliefs = out + (size_t)N_EDGES * (H + 2);

    const int EB = N_EDGES / 256;                 // 12500 exact

    // workspace layout (~257 MB; round-10 proved ws >= 283 MB)
    char* w = (char*)d_ws;
    __half* pernode  = (__half*)w;   w += (size_t)N_NODES * 64 * sizeof(__half);  // 12.8 MB
    float*  raw      = (float*)w;    w += (size_t)N_NODES * H * sizeof(float);    // 12.8 MB
    uint2*  slotmap  = (uint2*)w;    w += (size_t)N_EDGES * sizeof(uint2);        // 25.6 MB
    __half* hs       = (__half*)w;   w += (size_t)N_EDGES * H * sizeof(__half);   // 204.8 MB
    float*  W2       = (float*)w;    w += 4096;
    float*  Wfold    = (float*)w;    w += 4096;
    float*  c1       = (float*)w;    w += 128;
    float*  c0       = (float*)w;    w += 128;
    int*    cnt      = (int*)w;      w += sizeof(int) * N_NODES;
    int*    ptr      = (int*)w;      w += sizeof(int) * (N_NODES + 1);
    int*    fill     = (int*)w;      w += sizeof(int) * N_NODES;
    int*    bsum     = (int*)w;

    fold_kernel<<<1, 1024, 0, stream>>>(We, be, WN1, bN1, W2, Wfold, c1, c0);

    zero_int_kernel<<<SCAN_BLOCKS, 256, 0, stream>>>(cnt, N_NODES);
    hist_kernel<<<EB, 256, 0, stream>>>(eidx, cnt);
    scan_block_kernel<<<SCAN_BLOCKS, 256, 0, stream>>>(cnt, ptr, bsum);
    scan_bsum_kernel<<<1, 512, 0, stream>>>(bsum, SCAN_BLOCKS);
    scan_fix_kernel<<<SCAN_BLOCKS, 256, 0, stream>>>(ptr, fill, bsum, raw);

    scatter_big_kernel<<<EB, 256, 0, stream>>>(eidx, h_msg, fill, slotmap, hs);

    seg_stage_big_kernel<<<EB, 256, 0, stream>>>(hs, slotmap, raw);

    pernode_kernel<<<SCAN_BLOCKS, 256, 0, stream>>>(
        x, raw, ptr, W_in, b_in, Wn1, bn1, Wn2, bn2, W2, c1, c0, pernode);

    edge_fused_big_kernel<<<EB, 256, 0, stream>>>(
        hs, slotmap, pernode, Wfold, WN2, bN2, Wd, bd,
        out_hmsg, out_ymsg, raw);

    node_update_kernel<<<SCAN_BLOCKS, 256, 0, stream>>>(
        x, raw, W_in, b_in, WU, bU, Wb, bb, out_beliefs);
}

// Round 13
// 1038.135 us; speedup vs baseline: 1.7612x; 1.7612x over previous
//
#include <hip/hip_runtime.h>
#include <hip/hip_fp16.h>
#include <math.h>

#define N_NODES 100000
#define N_EDGES 3200000
#define H 32
#define SCAN_BLOCKS ((N_NODES + 255) / 256)   // 391
#define HSTRIDE 34                            // fp16 tile stride (conflict-free)

typedef float f32x4 __attribute__((ext_vector_type(4)));

__device__ __forceinline__ float lrelu(float v) { return v > 0.0f ? v : 0.01f * v; }

// ---- packed slot record: e (22b) | dst (17b) | src (17b) ----
__device__ __forceinline__ uint2 pack_eds(int e, int dst, int src) {
    uint2 r;
    r.x = (unsigned)e | ((unsigned)(dst & 0x3FF) << 22);
    r.y = ((unsigned)dst >> 10) | ((unsigned)src << 7);
    return r;
}
__device__ __forceinline__ int unpack_e(uint2 p)   { return (int)(p.x & 0x3FFFFF); }
__device__ __forceinline__ int unpack_dst(uint2 p) { return (int)((p.x >> 22) | ((p.y & 0x7F) << 10)); }
__device__ __forceinline__ int unpack_src(uint2 p) { return (int)(p.y >> 7); }

__device__ __forceinline__ void matvec32(const float* __restrict__ in,
                                         const float* __restrict__ W,
                                         const float* __restrict__ bias,
                                         float* __restrict__ out) {
#pragma unroll
    for (int o = 0; o < H; ++o) out[o] = bias[o];
#pragma unroll
    for (int k = 0; k < H; ++k) {
        float v = in[k];
#pragma unroll
        for (int o = 0; o < H; ++o) out[o] = fmaf(v, W[k * H + o], out[o]);
    }
}

__device__ __forceinline__ void matvec32_acc(const float* __restrict__ in,
                                             const float* __restrict__ W,
                                             float* __restrict__ out) {
#pragma unroll
    for (int k = 0; k < H; ++k) {
        float v = in[k];
#pragma unroll
        for (int o = 0; o < H; ++o) out[o] = fmaf(v, W[k * H + o], out[o]);
    }
}

__device__ __forceinline__ void load_row32(const float* __restrict__ p, float* __restrict__ r) {
    const f32x4* p4 = reinterpret_cast<const f32x4*>(p);
#pragma unroll
    for (int q = 0; q < 8; ++q) {
        f32x4 v = p4[q];
        r[4 * q + 0] = v.x; r[4 * q + 1] = v.y; r[4 * q + 2] = v.z; r[4 * q + 3] = v.w;
    }
}

// non-temporal row load (read-once stream; keep L3 for hs)
__device__ __forceinline__ void load_row32_nt(const float* __restrict__ p, float* __restrict__ r) {
    const f32x4* p4 = reinterpret_cast<const f32x4*>(p);
#pragma unroll
    for (int q = 0; q < 8; ++q) {
        f32x4 v = __builtin_nontemporal_load(p4 + q);
        r[4 * q + 0] = v.x; r[4 * q + 1] = v.y; r[4 * q + 2] = v.z; r[4 * q + 3] = v.w;
    }
}

// regular row store (L2 write-combining — nt stores tripled WRITE_SIZE in R12)
__device__ __forceinline__ void store_row32(float* __restrict__ p, const float* __restrict__ r) {
    f32x4* p4 = reinterpret_cast<f32x4*>(p);
#pragma unroll
    for (int q = 0; q < 8; ++q) {
        f32x4 v;
        v.x = r[4 * q + 0]; v.y = r[4 * q + 1]; v.z = r[4 * q + 2]; v.w = r[4 * q + 3];
        p4[q] = v;
    }
}

__device__ __forceinline__ void load_row32_h(const __half2* __restrict__ p, float* __restrict__ r) {
#pragma unroll
    for (int q = 0; q < 16; ++q) {
        float2 f = __half22float2(p[q]);
        r[2 * q + 0] = f.x; r[2 * q + 1] = f.y;
    }
}

__device__ __forceinline__ void store_row32_h(__half2* __restrict__ p, const float* __restrict__ r) {
#pragma unroll
    for (int q = 0; q < 16; ++q) p[q] = __floats2half2_rn(r[2 * q], r[2 * q + 1]);
}

__device__ __forceinline__ void hnode_row(const float* __restrict__ x, int i,
                                          const float* __restrict__ W_in,
                                          const float* __restrict__ b_in,
                                          float* __restrict__ r) {
    float x0 = x[(size_t)i * 3 + 0], x1 = x[(size_t)i * 3 + 1], x2 = x[(size_t)i * 3 + 2];
#pragma unroll
    for (int o = 0; o < H; ++o)
        r[o] = fmaf(x2, W_in[2 * H + o], fmaf(x1, W_in[1 * H + o], fmaf(x0, W_in[0 * H + o], b_in[o])));
}

// per-group segment scan over 32 staged fp16 LDS slots; lane owns one channel.
__device__ __forceinline__ void seg_scan32_h(const __half* __restrict__ tile,
                                             const int* __restrict__ nid,
                                             int base, int lane,
                                             float* __restrict__ out) {
    int cur = nid[base];
    float acc = __half2float(tile[base * HSTRIDE + lane]);
    bool started = false;
#pragma unroll 4
    for (int j = 1; j < 32; ++j) {
        int n = nid[base + j];
        float v = __half2float(tile[(base + j) * HSTRIDE + lane]);
        if (n != cur) {
            if (started) out[(size_t)cur * H + lane] = acc;
            else atomicAdd(out + (size_t)cur * H + lane, acc);
            started = true;
            cur = n;
            acc = v;
        } else {
            acc += v;
        }
    }
    atomicAdd(out + (size_t)cur * H + lane, acc);
}

__device__ __forceinline__ void staged_segsum(const float* __restrict__ m,
                                              int dst, int tid,
                                              __half* __restrict__ tile,
                                              int* __restrict__ nid,
                                              float* __restrict__ out) {
    nid[tid] = dst;
    __half2* row = reinterpret_cast<__half2*>(tile + tid * HSTRIDE);
#pragma unroll
    for (int q = 0; q < 16; ++q) row[q] = __floats2half2_rn(m[2 * q], m[2 * q + 1]);
    __syncthreads();
    seg_scan32_h(tile, nid, tid & ~31, tid & 31, out);
}

// ---------------- fold ----------------
__global__ __launch_bounds__(1024) void fold_kernel(const float* __restrict__ We,
                                                    const float* __restrict__ be,
                                                    const float* __restrict__ WN1,
                                                    const float* __restrict__ bN1,
                                                    float* __restrict__ W2,
                                                    float* __restrict__ Wfold,
                                                    float* __restrict__ c1,
                                                    float* __restrict__ c0) {
    int t = threadIdx.x;
    int k = t >> 5, o = t & 31;
    float s2 = 0.0f, sf = 0.0f;
#pragma unroll
    for (int j = 0; j < H; ++j) {
        float w = We[k * H + j];
        s2 = fmaf(w, WN1[j * H + o], s2);
        sf = fmaf(w, WN1[(H + j) * H + o], sf);
    }
    W2[t] = s2;
    Wfold[t] = sf;
    if (k == 0) {
        float a = 0.0f, b = 0.0f;
#pragma unroll
        for (int j = 0; j < H; ++j) {
            a = fmaf(be[j], WN1[j * H + o], a);
            b = fmaf(be[j], WN1[(H + j) * H + o], b);
        }
        c1[o] = a;
        c0[o] = bN1[o] + b;
    }
}

// ---------------- utility ----------------
__global__ __launch_bounds__(256) void zero_int_kernel(int* __restrict__ p, int n) {
    int i = blockIdx.x * blockDim.x + threadIdx.x;
    if (i < n) p[i] = 0;
}

// ---------------- CSR build ----------------
__global__ __launch_bounds__(256) void hist_kernel(const int* __restrict__ eidx, int* __restrict__ cnt) {
    int e = blockIdx.x * blockDim.x + threadIdx.x;
    if (e >= N_EDGES) return;
    atomicAdd(&cnt[eidx[(size_t)N_EDGES + e]], 1);
}

__global__ __launch_bounds__(256) void scan_block_kernel(const int* __restrict__ cnt,
                                                         int* __restrict__ ptr,
                                                         int* __restrict__ bsum) {
    __shared__ int sm[256];
    int idx = blockIdx.x * 256 + threadIdx.x;
    int v = (idx < N_NODES) ? cnt[idx] : 0;
    sm[threadIdx.x] = v;
    __syncthreads();
    for (int off = 1; off < 256; off <<= 1) {
        int t = (threadIdx.x >= off) ? sm[threadIdx.x - off] : 0;
        __syncthreads();
        sm[threadIdx.x] += t;
        __syncthreads();
    }
    if (idx < N_NODES) ptr[idx] = sm[threadIdx.x] - v;
    if (threadIdx.x == 255) bsum[blockIdx.x] = sm[255];
}

__global__ __launch_bounds__(512) void scan_bsum_kernel(int* __restrict__ bsum, int nb) {
    __shared__ int sm[512];
    int v = (threadIdx.x < nb) ? bsum[threadIdx.x] : 0;
    sm[threadIdx.x] = v;
    __syncthreads();
    for (int off = 1; off < 512; off <<= 1) {
        int t = (threadIdx.x >= off) ? sm[threadIdx.x - off] : 0;
        __syncthreads();
        sm[threadIdx.x] += t;
        __syncthreads();
    }
    if (threadIdx.x < nb) bsum[threadIdx.x] = sm[threadIdx.x] - v;
}

// add block offsets; init fill=ptr; zero raw (pre-seg_stage); set ptr[N]
__global__ __launch_bounds__(256) void scan_fix_kernel(int* __restrict__ ptr,
                                                       int* __restrict__ fill,
                                                       const int* __restrict__ bsum,
                                                       float* __restrict__ raw) {
    int idx = blockIdx.x * 256 + threadIdx.x;
    if (idx < N_NODES) {
        int p = ptr[idx] + bsum[blockIdx.x];
        ptr[idx] = p;
        fill[idx] = p;
        f32x4 z = (f32x4)(0.0f);
        f32x4* r4 = reinterpret_cast<f32x4*>(raw + (size_t)idx * H);
#pragma unroll
        for (int q = 0; q < 8; ++q) r4[q] = z;
    }
    if (idx == 0) ptr[N_NODES] = N_EDGES;
}

// scatter: materialize slot-sorted fp16 h_msg + packed {e,dst,src}
__global__ __launch_bounds__(256) void scatter_big_kernel(const int* __restrict__ eidx,
                                                          const float* __restrict__ h_msg,
                                                          int* __restrict__ fill,
                                                          uint2* __restrict__ slotmap,
                                                          __half* __restrict__ hs) {
    int e = blockIdx.x * blockDim.x + threadIdx.x;
    if (e >= N_EDGES) return;
    int src = eidx[e];
    int dst = eidx[(size_t)N_EDGES + e];
    float m[H];
    load_row32_nt(h_msg + (size_t)e * H, m);       // read-once stream: keep out of L3
    int pos = atomicAdd(&fill[dst], 1);
    slotmap[pos] = pack_eds(e, dst, src);          // 8B random write
    store_row32_h(reinterpret_cast<__half2*>(hs + (size_t)pos * H), m); // 64B sector
}

__global__ __launch_bounds__(256) void seg_stage_big_kernel(const __half* __restrict__ hs,
                                                            const uint2* __restrict__ slotmap,
                                                            float* __restrict__ out) {
    __shared__ __half tile[256 * HSTRIDE];
    __shared__ int nid[256];
    int tid = threadIdx.x;
    int slot = blockIdx.x * 256 + tid;
    nid[tid] = unpack_dst(slotmap[slot]);
    const __half2* row = reinterpret_cast<const __half2*>(hs + (size_t)slot * H);  // sequential, L3-hot
    __half2* trow = reinterpret_cast<__half2*>(tile + tid * HSTRIDE);
#pragma unroll
    for (int q = 0; q < 16; ++q) trow[q] = row[q];
    __syncthreads();
    seg_scan32_h(tile, nid, tid & ~31, tid & 31, out);
}

// ---------------- per-node: pre1 + nn MLP -> fp16 pernode[n][64]; re-zeros raw ----------------
__global__ __launch_bounds__(256) void pernode_kernel(const float* __restrict__ x,
                                                      float* __restrict__ raw,
                                                      const int* __restrict__ ptr,
                                                      const float* __restrict__ W_in,
                                                      const float* __restrict__ b_in,
                                                      const float* __restrict__ Wn1,
                                                      const float* __restrict__ bn1,
                                                      const float* __restrict__ Wn2,
                                                      const float* __restrict__ bn2,
                                                      const float* __restrict__ W2,
                                                      const float* __restrict__ c1,
                                                      const float* __restrict__ c0,
                                                      __half* __restrict__ pernode) {
    int i = blockIdx.x * blockDim.x + threadIdx.x;
    if (i >= N_NODES) return;
    float s[H], p1[H];
    __half2* row = reinterpret_cast<__half2*>(pernode + (size_t)i * 64);
    load_row32(raw + (size_t)i * H, s);
    // re-zero raw for the aggr_out accumulation in edge_fused (same slot reuse)
    {
        f32x4 z = (f32x4)(0.0f);
        f32x4* r4 = reinterpret_cast<f32x4*>(raw + (size_t)i * H);
#pragma unroll
        for (int q = 0; q < 8; ++q) r4[q] = z;
    }
    float deg = (float)(ptr[i + 1] - ptr[i]);
#pragma unroll
    for (int o = 0; o < H; ++o) p1[o] = fmaf(deg, c1[o], c0[o]);
    matvec32_acc(s, W2, p1);
    store_row32_h(row, p1);
    hnode_row(x, i, W_in, b_in, s);
    matvec32(s, Wn1, bn1, p1);
#pragma unroll
    for (int o = 0; o < H; ++o) p1[o] = lrelu(p1[o]);
    matvec32(p1, Wn2, bn2, s);
#pragma unroll
    for (int o = 0; o < H; ++o) s[o] = lrelu(s[o]);
    store_row32_h(row + 16, s);
}

// ---------------- fused pass2 ----------------
__global__ __launch_bounds__(256) void edge_fused_big_kernel(
    const __half* __restrict__ hs, const uint2* __restrict__ slotmap,
    const __half* __restrict__ pernode,
    const float* __restrict__ Wfold,
    const float* __restrict__ WN2, const float* __restrict__ bN2,
    const float* __restrict__ Wd, const float* __restrict__ bd,
    float* __restrict__ out_hmsg, float* __restrict__ out_ymsg,
    float* __restrict__ aggr_out) {
    __shared__ __half tile[256 * HSTRIDE];
    __shared__ int nid[256];
    int tid = threadIdx.x;
    int slot = blockIdx.x * 256 + tid;
    uint2 sm = slotmap[slot];                       // sequential 8B
    int e = unpack_e(sm), dst = unpack_dst(sm), src = unpack_src(sm);

    float m[H], t[H], u[H];
    const __half2* pn = reinterpret_cast<const __half2*>(pernode + (size_t)src * 64);

    load_row32_h(reinterpret_cast<const __half2*>(hs + (size_t)slot * H), m);  // sequential, L3-hot
    load_row32_h(pn, t);                            // remaining random gather
    matvec32_acc(m, Wfold, t);
#pragma unroll
    for (int o = 0; o < H; ++o) t[o] = lrelu(t[o]);

    matvec32(t, WN2, bN2, u);

    load_row32_h(pn + 16, t);
#pragma unroll
    for (int o = 0; o < H; ++o) m[o] = t[o] + lrelu(u[o]);

    store_row32(out_hmsg + (size_t)e * H, m);       // regular store (L2 combines)

    float z0 = bd[0], z1 = bd[1];
#pragma unroll
    for (int k = 0; k < H; ++k) {
        z0 = fmaf(m[k], Wd[k * 2 + 0], z0);
        z1 = fmaf(m[k], Wd[k * 2 + 1], z1);
    }
    float zm = fmaxf(z0, z1);
    float e0 = __expf(z0 - zm), e1 = __expf(z1 - zm);
    float inv = 1.0f / (e0 + e1);
    *reinterpret_cast<float2*>(out_ymsg + (size_t)e * 2) = make_float2(e0 * inv, e1 * inv);

    staged_segsum(m, dst, tid, tile, nid, aggr_out);
}

// ---------------- node update + beliefs ----------------
__global__ __launch_bounds__(256) void node_update_kernel(
    const float* __restrict__ x, const float* __restrict__ aggr_out,
    const float* __restrict__ W_in, const float* __restrict__ b_in,
    const float* __restrict__ WU, const float* __restrict__ bU,
    const float* __restrict__ Wb, const float* __restrict__ bb,
    float* __restrict__ out_beliefs) {
    int i = blockIdx.x * blockDim.x + threadIdx.x;
    if (i >= N_NODES) return;
    float a[H], t[H];
    hnode_row(x, i, W_in, b_in, a);
    matvec32(a, WU, bU, t);
    load_row32(aggr_out + (size_t)i * H, a);
    matvec32_acc(a, WU + H * H, t);
#pragma unroll
    for (int o = 0; o < H; ++o) t[o] = lrelu(t[o]);

    if (x[(size_t)i * 3] == 1.0f) {
        float z0 = bb[0], z1 = bb[1];
#pragma unroll
        for (int k = 0; k < H; ++k) {
            z0 = fmaf(t[k], Wb[k * 2 + 0], z0);
            z1 = fmaf(t[k], Wb[k * 2 + 1], z1);
        }
        float zm = fmaxf(z0, z1);
        float e0 = __expf(z0 - zm), e1 = __expf(z1 - zm);
        float inv = 1.0f / (e0 + e1);
        out_beliefs[(size_t)i * 2 + 0] = e0 * inv;
        out_beliefs[(size_t)i * 2 + 1] = e1 * inv;
    }
}

extern "C" void kernel_launch(void* const* d_in, const int* in_sizes, int n_in,
                              void* d_out, int out_size, void* d_ws, size_t ws_size,
                              hipStream_t stream) {
    const float* x     = (const float*)d_in[0];
    const int*   eidx  = (const int*)d_in[1];
    const float* h_msg = (const float*)d_in[2];
    const float* W_in = (const float*)d_in[3];  const float* b_in = (const float*)d_in[4];
    const float* We   = (const float*)d_in[5];  const float* be   = (const float*)d_in[6];
    const float* Wn1  = (const float*)d_in[7];  const float* bn1  = (const float*)d_in[8];
    const float* Wn2  = (const float*)d_in[9];  const float* bn2  = (const float*)d_in[10];
    const float* WN1  = (const float*)d_in[11]; const float* bN1  = (const float*)d_in[12];
    const float* WN2  = (const float*)d_in[13]; const float* bN2  = (const float*)d_in[14];
    const float* WU   = (const float*)d_in[15]; const float* bU   = (const float*)d_in[16];
    const float* Wd   = (const float*)d_in[17]; const float* bd   = (const float*)d_in[18];
    const float* Wb   = (const float*)d_in[19]; const float* bb   = (const float*)d_in[20];

    float* out         = (float*)d_out;
    float* out_hmsg    = out;
    float* out_ymsg    = out + (size_t)N_EDGES * H;
    float* out_beliefs = out + (size_t)N_EDGES * (H + 2);

    const int EB = N_EDGES / 256;                 // 12500 exact

    // workspace layout (~257 MB; round-10 proved ws >= 283 MB)
    char* w = (char*)d_ws;
    __half* pernode  = (__half*)w;   w += (size_t)N_NODES * 64 * sizeof(__half);  // 12.8 MB
    float*  raw      = (float*)w;    w += (size_t)N_NODES * H * sizeof(float);    // 12.8 MB
    uint2*  slotmap  = (uint2*)w;    w += (size_t)N_EDGES * sizeof(uint2);        // 25.6 MB
    __half* hs       = (__half*)w;   w += (size_t)N_EDGES * H * sizeof(__half);   // 204.8 MB
    float*  W2       = (float*)w;    w += 4096;
    float*  Wfold    = (float*)w;    w += 4096;
    float*  c1       = (float*)w;    w += 128;
    float*  c0       = (float*)w;    w += 128;
    int*    cnt      = (int*)w;      w += sizeof(int) * N_NODES;
    int*    ptr      = (int*)w;      w += sizeof(int) * (N_NODES + 1);
    int*    fill     = (int*)w;      w += sizeof(int) * N_NODES;
    int*    bsum     = (int*)w;

    fold_kernel<<<1, 1024, 0, stream>>>(We, be, WN1, bN1, W2, Wfold, c1, c0);

    zero_int_kernel<<<SCAN_BLOCKS, 256, 0, stream>>>(cnt, N_NODES);
    hist_kernel<<<EB, 256, 0, stream>>>(eidx, cnt);
    scan_block_kernel<<<SCAN_BLOCKS, 256, 0, stream>>>(cnt, ptr, bsum);
    scan_bsum_kernel<<<1, 512, 0, stream>>>(bsum, SCAN_BLOCKS);
    scan_fix_kernel<<<SCAN_BLOCKS, 256, 0, stream>>>(ptr, fill, bsum, raw);

    scatter_big_kernel<<<EB, 256, 0, stream>>>(eidx, h_msg, fill, slotmap, hs);

    seg_stage_big_kernel<<<EB, 256, 0, stream>>>(hs, slotmap, raw);

    pernode_kernel<<<SCAN_BLOCKS, 256, 0, stream>>>(
        x, raw, ptr, W_in, b_in, Wn1, bn1, Wn2, bn2, W2, c1, c0, pernode);

    edge_fused_big_kernel<<<EB, 256, 0, stream>>>(
        hs, slotmap, pernode, Wfold, WN2, bN2, Wd, bd,
        out_hmsg, out_ymsg, raw);

    node_update_kernel<<<SCAN_BLOCKS, 256, 0, stream>>>(
        x, raw, W_in, b_in, WU, bU, Wb, bb, out_beliefs);
}

// Round 14
// 873.002 us; speedup vs baseline: 2.0943x; 1.1892x over previous
//
#include <hip/hip_runtime.h>
#include <hip/hip_fp16.h>
#include <math.h>

#define N_NODES 100000
#define N_EDGES 3200000
#define H 32
#define SCAN_BLOCKS ((N_NODES + 255) / 256)   // 391
#define HSTRIDE 34                            // fp16 tile stride (conflict-free)

typedef float f32x4 __attribute__((ext_vector_type(4)));

__device__ __forceinline__ float lrelu(float v) { return v > 0.0f ? v : 0.01f * v; }

// ---- packed slot record: e (22b) | dst (17b) | src (17b) ----
__device__ __forceinline__ uint2 pack_eds(int e, int dst, int src) {
    uint2 r;
    r.x = (unsigned)e | ((unsigned)(dst & 0x3FF) << 22);
    r.y = ((unsigned)dst >> 10) | ((unsigned)src << 7);
    return r;
}
__device__ __forceinline__ int unpack_e(uint2 p)   { return (int)(p.x & 0x3FFFFF); }
__device__ __forceinline__ int unpack_dst(uint2 p) { return (int)((p.x >> 22) | ((p.y & 0x7F) << 10)); }
__device__ __forceinline__ int unpack_src(uint2 p) { return (int)(p.y >> 7); }

__device__ __forceinline__ void matvec32(const float* __restrict__ in,
                                         const float* __restrict__ W,
                                         const float* __restrict__ bias,
                                         float* __restrict__ out) {
#pragma unroll
    for (int o = 0; o < H; ++o) out[o] = bias[o];
#pragma unroll
    for (int k = 0; k < H; ++k) {
        float v = in[k];
#pragma unroll
        for (int o = 0; o < H; ++o) out[o] = fmaf(v, W[k * H + o], out[o]);
    }
}

__device__ __forceinline__ void matvec32_acc(const float* __restrict__ in,
                                             const float* __restrict__ W,
                                             float* __restrict__ out) {
#pragma unroll
    for (int k = 0; k < H; ++k) {
        float v = in[k];
#pragma unroll
        for (int o = 0; o < H; ++o) out[o] = fmaf(v, W[k * H + o], out[o]);
    }
}

__device__ __forceinline__ void load_row32(const float* __restrict__ p, float* __restrict__ r) {
    const f32x4* p4 = reinterpret_cast<const f32x4*>(p);
#pragma unroll
    for (int q = 0; q < 8; ++q) {
        f32x4 v = p4[q];
        r[4 * q + 0] = v.x; r[4 * q + 1] = v.y; r[4 * q + 2] = v.z; r[4 * q + 3] = v.w;
    }
}

__device__ __forceinline__ void store_row32(float* __restrict__ p, const float* __restrict__ r) {
    f32x4* p4 = reinterpret_cast<f32x4*>(p);
#pragma unroll
    for (int q = 0; q < 8; ++q) {
        f32x4 v;
        v.x = r[4 * q + 0]; v.y = r[4 * q + 1]; v.z = r[4 * q + 2]; v.w = r[4 * q + 3];
        p4[q] = v;
    }
}

__device__ __forceinline__ void load_row32_h(const __half2* __restrict__ p, float* __restrict__ r) {
#pragma unroll
    for (int q = 0; q < 16; ++q) {
        float2 f = __half22float2(p[q]);
        r[2 * q + 0] = f.x; r[2 * q + 1] = f.y;
    }
}

__device__ __forceinline__ void store_row32_h(__half2* __restrict__ p, const float* __restrict__ r) {
#pragma unroll
    for (int q = 0; q < 16; ++q) p[q] = __floats2half2_rn(r[2 * q], r[2 * q + 1]);
}

__device__ __forceinline__ void hnode_row(const float* __restrict__ x, int i,
                                          const float* __restrict__ W_in,
                                          const float* __restrict__ b_in,
                                          float* __restrict__ r) {
    float x0 = x[(size_t)i * 3 + 0], x1 = x[(size_t)i * 3 + 1], x2 = x[(size_t)i * 3 + 2];
#pragma unroll
    for (int o = 0; o < H; ++o)
        r[o] = fmaf(x2, W_in[2 * H + o], fmaf(x1, W_in[1 * H + o], fmaf(x0, W_in[0 * H + o], b_in[o])));
}

// per-group segment scan over 32 staged fp16 LDS slots; lane owns one channel.
__device__ __forceinline__ void seg_scan32_h(const __half* __restrict__ tile,
                                             const int* __restrict__ nid,
                                             int base, int lane,
                                             float* __restrict__ out) {
    int cur = nid[base];
    float acc = __half2float(tile[base * HSTRIDE + lane]);
    bool started = false;
#pragma unroll 4
    for (int j = 1; j < 32; ++j) {
        int n = nid[base + j];
        float v = __half2float(tile[(base + j) * HSTRIDE + lane]);
        if (n != cur) {
            if (started) out[(size_t)cur * H + lane] = acc;
            else atomicAdd(out + (size_t)cur * H + lane, acc);
            started = true;
            cur = n;
            acc = v;
        } else {
            acc += v;
        }
    }
    atomicAdd(out + (size_t)cur * H + lane, acc);
}

__device__ __forceinline__ void staged_segsum(const float* __restrict__ m,
                                              int dst, int tid,
                                              __half* __restrict__ tile,
                                              int* __restrict__ nid,
                                              float* __restrict__ out) {
    nid[tid] = dst;
    __half2* row = reinterpret_cast<__half2*>(tile + tid * HSTRIDE);
#pragma unroll
    for (int q = 0; q < 16; ++q) row[q] = __floats2half2_rn(m[2 * q], m[2 * q + 1]);
    __syncthreads();
    seg_scan32_h(tile, nid, tid & ~31, tid & 31, out);
}

// ---------------- fold ----------------
__global__ __launch_bounds__(1024) void fold_kernel(const float* __restrict__ We,
                                                    const float* __restrict__ be,
                                                    const float* __restrict__ WN1,
                                                    const float* __restrict__ bN1,
                                                    float* __restrict__ W2,
                                                    float* __restrict__ Wfold,
                                                    float* __restrict__ c1,
                                                    float* __restrict__ c0) {
    int t = threadIdx.x;
    int k = t >> 5, o = t & 31;
    float s2 = 0.0f, sf = 0.0f;
#pragma unroll
    for (int j = 0; j < H; ++j) {
        float w = We[k * H + j];
        s2 = fmaf(w, WN1[j * H + o], s2);
        sf = fmaf(w, WN1[(H + j) * H + o], sf);
    }
    W2[t] = s2;
    Wfold[t] = sf;
    if (k == 0) {
        float a = 0.0f, b = 0.0f;
#pragma unroll
        for (int j = 0; j < H; ++j) {
            a = fmaf(be[j], WN1[j * H + o], a);
            b = fmaf(be[j], WN1[(H + j) * H + o], b);
        }
        c1[o] = a;
        c0[o] = bN1[o] + b;
    }
}

// ---------------- utility ----------------
__global__ __launch_bounds__(256) void zero_int_kernel(int* __restrict__ p, int n) {
    int i = blockIdx.x * blockDim.x + threadIdx.x;
    if (i < n) p[i] = 0;
}

// ---------------- CSR build ----------------
__global__ __launch_bounds__(256) void hist_kernel(const int* __restrict__ eidx, int* __restrict__ cnt) {
    int e = blockIdx.x * blockDim.x + threadIdx.x;
    if (e >= N_EDGES) return;
    atomicAdd(&cnt[eidx[(size_t)N_EDGES + e]], 1);
}

__global__ __launch_bounds__(256) void scan_block_kernel(const int* __restrict__ cnt,
                                                         int* __restrict__ ptr,
                                                         int* __restrict__ bsum) {
    __shared__ int sm[256];
    int idx = blockIdx.x * 256 + threadIdx.x;
    int v = (idx < N_NODES) ? cnt[idx] : 0;
    sm[threadIdx.x] = v;
    __syncthreads();
    for (int off = 1; off < 256; off <<= 1) {
        int t = (threadIdx.x >= off) ? sm[threadIdx.x - off] : 0;
        __syncthreads();
        sm[threadIdx.x] += t;
        __syncthreads();
    }
    if (idx < N_NODES) ptr[idx] = sm[threadIdx.x] - v;
    if (threadIdx.x == 255) bsum[blockIdx.x] = sm[255];
}

__global__ __launch_bounds__(512) void scan_bsum_kernel(int* __restrict__ bsum, int nb) {
    __shared__ int sm[512];
    int v = (threadIdx.x < nb) ? bsum[threadIdx.x] : 0;
    sm[threadIdx.x] = v;
    __syncthreads();
    for (int off = 1; off < 512; off <<= 1) {
        int t = (threadIdx.x >= off) ? sm[threadIdx.x - off] : 0;
        __syncthreads();
        sm[threadIdx.x] += t;
        __syncthreads();
    }
    if (threadIdx.x < nb) bsum[threadIdx.x] = sm[threadIdx.x] - v;
}

// add block offsets; init fill=ptr; zero raw (pre-seg_stage); set ptr[N]
__global__ __launch_bounds__(256) void scan_fix_kernel(int* __restrict__ ptr,
                                                       int* __restrict__ fill,
                                                       const int* __restrict__ bsum,
                                                       float* __restrict__ raw) {
    int idx = blockIdx.x * 256 + threadIdx.x;
    if (idx < N_NODES) {
        int p = ptr[idx] + bsum[blockIdx.x];
        ptr[idx] = p;
        fill[idx] = p;
        f32x4 z = (f32x4)(0.0f);
        f32x4* r4 = reinterpret_cast<f32x4*>(raw + (size_t)idx * H);
#pragma unroll
        for (int q = 0; q < 8; ++q) r4[q] = z;
    }
    if (idx == 0) ptr[N_NODES] = N_EDGES;
}

// scatter: materialize slot-sorted fp16 h_msg + packed {e,dst,src}
// atomic issued BEFORE the row load so its L2 round-trip overlaps the 128B read
__global__ __launch_bounds__(256) void scatter_big_kernel(const int* __restrict__ eidx,
                                                          const float* __restrict__ h_msg,
                                                          int* __restrict__ fill,
                                                          uint2* __restrict__ slotmap,
                                                          __half* __restrict__ hs) {
    int e = blockIdx.x * blockDim.x + threadIdx.x;
    if (e >= N_EDGES) return;
    int src = eidx[e];
    int dst = eidx[(size_t)N_EDGES + e];
    int pos = atomicAdd(&fill[dst], 1);            // issue first: overlaps row load
    float m[H];
    load_row32(h_msg + (size_t)e * H, m);          // regular load (L3 residue hits)
    slotmap[pos] = pack_eds(e, dst, src);          // 8B random write
    store_row32_h(reinterpret_cast<__half2*>(hs + (size_t)pos * H), m); // 64B sector
}

__global__ __launch_bounds__(256) void seg_stage_big_kernel(const __half* __restrict__ hs,
                                                            const uint2* __restrict__ slotmap,
                                                            float* __restrict__ out) {
    __shared__ __half tile[256 * HSTRIDE];
    __shared__ int nid[256];
    int tid = threadIdx.x;
    int slot = blockIdx.x * 256 + tid;
    nid[tid] = unpack_dst(slotmap[slot]);
    const __half2* row = reinterpret_cast<const __half2*>(hs + (size_t)slot * H);  // sequential
    __half2* trow = reinterpret_cast<__half2*>(tile + tid * HSTRIDE);
#pragma unroll
    for (int q = 0; q < 16; ++q) trow[q] = row[q];
    __syncthreads();
    seg_scan32_h(tile, nid, tid & ~31, tid & 31, out);
}

// ---------------- per-node: pre1 + nn MLP -> fp16 pernode[n][64]; re-zeros raw ----------------
__global__ __launch_bounds__(256) void pernode_kernel(const float* __restrict__ x,
                                                      float* __restrict__ raw,
                                                      const int* __restrict__ ptr,
                                                      const float* __restrict__ W_in,
                                                      const float* __restrict__ b_in,
                                                      const float* __restrict__ Wn1,
                                                      const float* __restrict__ bn1,
                                                      const float* __restrict__ Wn2,
                                                      const float* __restrict__ bn2,
                                                      const float* __restrict__ W2,
                                                      const float* __restrict__ c1,
                                                      const float* __restrict__ c0,
                                                      __half* __restrict__ pernode) {
    int i = blockIdx.x * blockDim.x + threadIdx.x;
    if (i >= N_NODES) return;
    float s[H], p1[H];
    __half2* row = reinterpret_cast<__half2*>(pernode + (size_t)i * 64);
    load_row32(raw + (size_t)i * H, s);
    // re-zero raw for the aggr_out accumulation in edge_fused (same slot reuse)
    {
        f32x4 z = (f32x4)(0.0f);
        f32x4* r4 = reinterpret_cast<f32x4*>(raw + (size_t)i * H);
#pragma unroll
        for (int q = 0; q < 8; ++q) r4[q] = z;
    }
    float deg = (float)(ptr[i + 1] - ptr[i]);
#pragma unroll
    for (int o = 0; o < H; ++o) p1[o] = fmaf(deg, c1[o], c0[o]);
    matvec32_acc(s, W2, p1);
    store_row32_h(row, p1);
    hnode_row(x, i, W_in, b_in, s);
    matvec32(s, Wn1, bn1, p1);
#pragma unroll
    for (int o = 0; o < H; ++o) p1[o] = lrelu(p1[o]);
    matvec32(p1, Wn2, bn2, s);
#pragma unroll
    for (int o = 0; o < H; ++o) s[o] = lrelu(s[o]);
    store_row32_h(row + 16, s);
}

// ---------------- fused pass2 ----------------
__global__ __launch_bounds__(256) void edge_fused_big_kernel(
    const __half* __restrict__ hs, const uint2* __restrict__ slotmap,
    const __half* __restrict__ pernode,
    const float* __restrict__ Wfold,
    const float* __restrict__ WN2, const float* __restrict__ bN2,
    const float* __restrict__ Wd, const float* __restrict__ bd,
    float* __restrict__ out_hmsg, float* __restrict__ out_ymsg,
    float* __restrict__ aggr_out) {
    __shared__ __half tile[256 * HSTRIDE];
    __shared__ int nid[256];
    int tid = threadIdx.x;
    int slot = blockIdx.x * 256 + tid;
    uint2 sm = slotmap[slot];                       // sequential 8B
    int e = unpack_e(sm), dst = unpack_dst(sm), src = unpack_src(sm);

    float m[H], t[H], u[H];
    const __half2* pn = reinterpret_cast<const __half2*>(pernode + (size_t)src * 64);

    load_row32_h(reinterpret_cast<const __half2*>(hs + (size_t)slot * H), m);  // sequential
    load_row32_h(pn, t);                            // remaining random gather (L3)
    matvec32_acc(m, Wfold, t);
#pragma unroll
    for (int o = 0; o < H; ++o) t[o] = lrelu(t[o]);

    matvec32(t, WN2, bN2, u);

    load_row32_h(pn + 16, t);
#pragma unroll
    for (int o = 0; o < H; ++o) m[o] = t[o] + lrelu(u[o]);

    store_row32(out_hmsg + (size_t)e * H, m);       // regular store (L2 combines)

    float z0 = bd[0], z1 = bd[1];
#pragma unroll
    for (int k = 0; k < H; ++k) {
        z0 = fmaf(m[k], Wd[k * 2 + 0], z0);
        z1 = fmaf(m[k], Wd[k * 2 + 1], z1);
    }
    float zm = fmaxf(z0, z1);
    float e0 = __expf(z0 - zm), e1 = __expf(z1 - zm);
    float inv = 1.0f / (e0 + e1);
    *reinterpret_cast<float2*>(out_ymsg + (size_t)e * 2) = make_float2(e0 * inv, e1 * inv);

    staged_segsum(m, dst, tid, tile, nid, aggr_out);
}

// ---------------- node update + beliefs ----------------
__global__ __launch_bounds__(256) void node_update_kernel(
    const float* __restrict__ x, const float* __restrict__ aggr_out,
    const float* __restrict__ W_in, const float* __restrict__ b_in,
    const float* __restrict__ WU, const float* __restrict__ bU,
    const float* __restrict__ Wb, const float* __restrict__ bb,
    float* __restrict__ out_beliefs) {
    int i = blockIdx.x * blockDim.x + threadIdx.x;
    if (i >= N_NODES) return;
    float a[H], t[H];
    hnode_row(x, i, W_in, b_in, a);
    matvec32(a, WU, bU, t);
    load_row32(aggr_out + (size_t)i * H, a);
    matvec32_acc(a, WU + H * H, t);
#pragma unroll
    for (int o = 0; o < H; ++o) t[o] = lrelu(t[o]);

    if (x[(size_t)i * 3] == 1.0f) {
        float z0 = bb[0], z1 = bb[1];
#pragma unroll
        for (int k = 0; k < H; ++k) {
            z0 = fmaf(t[k], Wb[k * 2 + 0], z0);
            z1 = fmaf(t[k], Wb[k * 2 + 1], z1);
        }
        float zm = fmaxf(z0, z1);
        float e0 = __expf(z0 - zm), e1 = __expf(z1 - zm);
        float inv = 1.0f / (e0 + e1);
        out_beliefs[(size_t)i * 2 + 0] = e0 * inv;
        out_beliefs[(size_t)i * 2 + 1] = e1 * inv;
    }
}

extern "C" void kernel_launch(void* const* d_in, const int* in_sizes, int n_in,
                              void* d_out, int out_size, void* d_ws, size_t ws_size,
                              hipStream_t stream) {
    const float* x     = (const float*)d_in[0];
    const int*   eidx  = (const int*)d_in[1];
    const float* h_msg = (const float*)d_in[2];
    const float* W_in = (const float*)d_in[3];  const float* b_in = (const float*)d_in[4];
    const float* We   = (const float*)d_in[5];  const float* be   = (const float*)d_in[6];
    const float* Wn1  = (const float*)d_in[7];  const float* bn1  = (const float*)d_in[8];
    const float* Wn2  = (const float*)d_in[9];  const float* bn2  = (const float*)d_in[10];
    const float* WN1  = (const float*)d_in[11]; const float* bN1  = (const float*)d_in[12];
    const float* WN2  = (const float*)d_in[13]; const float* bN2  = (const float*)d_in[14];
    const float* WU   = (const float*)d_in[15]; const float* bU   = (const float*)d_in[16];
    const float* Wd   = (const float*)d_in[17]; const float* bd   = (const float*)d_in[18];
    const float* Wb   = (const float*)d_in[19]; const float* bb   = (const float*)d_in[20];

    float* out         = (float*)d_out;
    float* out_hmsg    = out;
    float* out_ymsg    = out + (size_t)N_EDGES * H;
    float* out_beliefs = out + (size_t)N_EDGES * (H + 2);

    const int EB = N_EDGES / 256;                 // 12500 exact

    // workspace layout (~257 MB; round-10 proved ws >= 283 MB)
    char* w = (char*)d_ws;
    __half* pernode  = (__half*)w;   w += (size_t)N_NODES * 64 * sizeof(__half);  // 12.8 MB
    float*  raw      = (float*)w;    w += (size_t)N_NODES * H * sizeof(float);    // 12.8 MB
    uint2*  slotmap  = (uint2*)w;    w += (size_t)N_EDGES * sizeof(uint2);        // 25.6 MB
    __half* hs       = (__half*)w;   w += (size_t)N_EDGES * H * sizeof(__half);   // 204.8 MB
    float*  W2       = (float*)w;    w += 4096;
    float*  Wfold    = (float*)w;    w += 4096;
    float*  c1       = (float*)w;    w += 128;
    float*  c0       = (float*)w;    w += 128;
    int*    cnt      = (int*)w;      w += sizeof(int) * N_NODES;
    int*    ptr      = (int*)w;      w += sizeof(int) * (N_NODES + 1);
    int*    fill     = (int*)w;      w += sizeof(int) * N_NODES;
    int*    bsum     = (int*)w;

    fold_kernel<<<1, 1024, 0, stream>>>(We, be, WN1, bN1, W2, Wfold, c1, c0);

    zero_int_kernel<<<SCAN_BLOCKS, 256, 0, stream>>>(cnt, N_NODES);
    hist_kernel<<<EB, 256, 0, stream>>>(eidx, cnt);
    scan_block_kernel<<<SCAN_BLOCKS, 256, 0, stream>>>(cnt, ptr, bsum);
    scan_bsum_kernel<<<1, 512, 0, stream>>>(bsum, SCAN_BLOCKS);
    scan_fix_kernel<<<SCAN_BLOCKS, 256, 0, stream>>>(ptr, fill, bsum, raw);

    scatter_big_kernel<<<EB, 256, 0, stream>>>(eidx, h_msg, fill, slotmap, hs);

    seg_stage_big_kernel<<<EB, 256, 0, stream>>>(hs, slotmap, raw);

    pernode_kernel<<<SCAN_BLOCKS, 256, 0, stream>>>(
        x, raw, ptr, W_in, b_in, Wn1, bn1, Wn2, bn2, W2, c1, c0, pernode);

    edge_fused_big_kernel<<<EB, 256, 0, stream>>>(
        hs, slotmap, pernode, Wfold, WN2, bN2, Wd, bd,
        out_hmsg, out_ymsg, raw);

    node_update_kernel<<<SCAN_BLOCKS, 256, 0, stream>>>(
        x, raw, W_in, b_in, WU, bU, Wb, bb, out_beliefs);
}

// Round 15
// 870.460 us; speedup vs baseline: 2.1004x; 1.0029x over previous
//
#include <hip/hip_runtime.h>
#include <hip/hip_fp16.h>
#include <math.h>

#define N_NODES 100000
#define N_EDGES 3200000
#define H 32
#define SCAN_BLOCKS ((N_NODES + 255) / 256)   // 391
#define HSTRIDE 34                            // fp16 tile stride (conflict-free)

typedef float f32x4 __attribute__((ext_vector_type(4)));

__device__ __forceinline__ float lrelu(float v) { return v > 0.0f ? v : 0.01f * v; }

// ---- packed slot record: e (22b) | dst (17b) | src (17b) ----
__device__ __forceinline__ uint2 pack_eds(int e, int dst, int src) {
    uint2 r;
    r.x = (unsigned)e | ((unsigned)(dst & 0x3FF) << 22);
    r.y = ((unsigned)dst >> 10) | ((unsigned)src << 7);
    return r;
}
__device__ __forceinline__ int unpack_e(uint2 p)   { return (int)(p.x & 0x3FFFFF); }
__device__ __forceinline__ int unpack_dst(uint2 p) { return (int)((p.x >> 22) | ((p.y & 0x7F) << 10)); }
__device__ __forceinline__ int unpack_src(uint2 p) { return (int)(p.y >> 7); }

__device__ __forceinline__ void matvec32(const float* __restrict__ in,
                                         const float* __restrict__ W,
                                         const float* __restrict__ bias,
                                         float* __restrict__ out) {
#pragma unroll
    for (int o = 0; o < H; ++o) out[o] = bias[o];
#pragma unroll
    for (int k = 0; k < H; ++k) {
        float v = in[k];
#pragma unroll
        for (int o = 0; o < H; ++o) out[o] = fmaf(v, W[k * H + o], out[o]);
    }
}

__device__ __forceinline__ void matvec32_acc(const float* __restrict__ in,
                                             const float* __restrict__ W,
                                             float* __restrict__ out) {
#pragma unroll
    for (int k = 0; k < H; ++k) {
        float v = in[k];
#pragma unroll
        for (int o = 0; o < H; ++o) out[o] = fmaf(v, W[k * H + o], out[o]);
    }
}

__device__ __forceinline__ void load_row32(const float* __restrict__ p, float* __restrict__ r) {
    const f32x4* p4 = reinterpret_cast<const f32x4*>(p);
#pragma unroll
    for (int q = 0; q < 8; ++q) {
        f32x4 v = p4[q];
        r[4 * q + 0] = v.x; r[4 * q + 1] = v.y; r[4 * q + 2] = v.z; r[4 * q + 3] = v.w;
    }
}

__device__ __forceinline__ void store_row32(float* __restrict__ p, const float* __restrict__ r) {
    f32x4* p4 = reinterpret_cast<f32x4*>(p);
#pragma unroll
    for (int q = 0; q < 8; ++q) {
        f32x4 v;
        v.x = r[4 * q + 0]; v.y = r[4 * q + 1]; v.z = r[4 * q + 2]; v.w = r[4 * q + 3];
        p4[q] = v;
    }
}

__device__ __forceinline__ void load_row32_h(const __half2* __restrict__ p, float* __restrict__ r) {
#pragma unroll
    for (int q = 0; q < 16; ++q) {
        float2 f = __half22float2(p[q]);
        r[2 * q + 0] = f.x; r[2 * q + 1] = f.y;
    }
}

__device__ __forceinline__ void store_row32_h(__half2* __restrict__ p, const float* __restrict__ r) {
#pragma unroll
    for (int q = 0; q < 16; ++q) p[q] = __floats2half2_rn(r[2 * q], r[2 * q + 1]);
}

__device__ __forceinline__ void hnode_row(const float* __restrict__ x, int i,
                                          const float* __restrict__ W_in,
                                          const float* __restrict__ b_in,
                                          float* __restrict__ r) {
    float x0 = x[(size_t)i * 3 + 0], x1 = x[(size_t)i * 3 + 1], x2 = x[(size_t)i * 3 + 2];
#pragma unroll
    for (int o = 0; o < H; ++o)
        r[o] = fmaf(x2, W_in[2 * H + o], fmaf(x1, W_in[1 * H + o], fmaf(x0, W_in[0 * H + o], b_in[o])));
}

// per-group segment scan over 32 staged fp16 LDS slots; lane owns one channel.
__device__ __forceinline__ void seg_scan32_h(const __half* __restrict__ tile,
                                             const int* __restrict__ nid,
                                             int base, int lane,
                                             float* __restrict__ out) {
    int cur = nid[base];
    float acc = __half2float(tile[base * HSTRIDE + lane]);
    bool started = false;
#pragma unroll 4
    for (int j = 1; j < 32; ++j) {
        int n = nid[base + j];
        float v = __half2float(tile[(base + j) * HSTRIDE + lane]);
        if (n != cur) {
            if (started) out[(size_t)cur * H + lane] = acc;
            else atomicAdd(out + (size_t)cur * H + lane, acc);
            started = true;
            cur = n;
            acc = v;
        } else {
            acc += v;
        }
    }
    atomicAdd(out + (size_t)cur * H + lane, acc);
}

// stage + scan. Scan group (32 slots) is HALF A WAVE64 -> no block barrier needed:
// LDS RAW within one wave is ordered by compiler-inserted lgkmcnt. wave_barrier()
// is a zero-cost scheduling fence to keep the compiler from reordering.
__device__ __forceinline__ void staged_segsum(const float* __restrict__ m,
                                              int dst, int tid,
                                              __half* __restrict__ tile,
                                              int* __restrict__ nid,
                                              float* __restrict__ out) {
    nid[tid] = dst;
    __half2* row = reinterpret_cast<__half2*>(tile + tid * HSTRIDE);
#pragma unroll
    for (int q = 0; q < 16; ++q) row[q] = __floats2half2_rn(m[2 * q], m[2 * q + 1]);
    __builtin_amdgcn_wave_barrier();
    seg_scan32_h(tile, nid, tid & ~31, tid & 31, out);
}

// ---------------- fold ----------------
__global__ __launch_bounds__(1024) void fold_kernel(const float* __restrict__ We,
                                                    const float* __restrict__ be,
                                                    const float* __restrict__ WN1,
                                                    const float* __restrict__ bN1,
                                                    float* __restrict__ W2,
                                                    float* __restrict__ Wfold,
                                                    float* __restrict__ c1,
                                                    float* __restrict__ c0) {
    int t = threadIdx.x;
    int k = t >> 5, o = t & 31;
    float s2 = 0.0f, sf = 0.0f;
#pragma unroll
    for (int j = 0; j < H; ++j) {
        float w = We[k * H + j];
        s2 = fmaf(w, WN1[j * H + o], s2);
        sf = fmaf(w, WN1[(H + j) * H + o], sf);
    }
    W2[t] = s2;
    Wfold[t] = sf;
    if (k == 0) {
        float a = 0.0f, b = 0.0f;
#pragma unroll
        for (int j = 0; j < H; ++j) {
            a = fmaf(be[j], WN1[j * H + o], a);
            b = fmaf(be[j], WN1[(H + j) * H + o], b);
        }
        c1[o] = a;
        c0[o] = bN1[o] + b;
    }
}

// ---------------- utility ----------------
__global__ __launch_bounds__(256) void zero_int_kernel(int* __restrict__ p, int n) {
    int i = blockIdx.x * blockDim.x + threadIdx.x;
    if (i < n) p[i] = 0;
}

// ---------------- CSR build ----------------
__global__ __launch_bounds__(256) void hist_kernel(const int* __restrict__ eidx, int* __restrict__ cnt) {
    int e = blockIdx.x * blockDim.x + threadIdx.x;
    if (e >= N_EDGES) return;
    atomicAdd(&cnt[eidx[(size_t)N_EDGES + e]], 1);
}

__global__ __launch_bounds__(256) void scan_block_kernel(const int* __restrict__ cnt,
                                                         int* __restrict__ ptr,
                                                         int* __restrict__ bsum) {
    __shared__ int sm[256];
    int idx = blockIdx.x * 256 + threadIdx.x;
    int v = (idx < N_NODES) ? cnt[idx] : 0;
    sm[threadIdx.x] = v;
    __syncthreads();
    for (int off = 1; off < 256; off <<= 1) {
        int t = (threadIdx.x >= off) ? sm[threadIdx.x - off] : 0;
        __syncthreads();
        sm[threadIdx.x] += t;
        __syncthreads();
    }
    if (idx < N_NODES) ptr[idx] = sm[threadIdx.x] - v;
    if (threadIdx.x == 255) bsum[blockIdx.x] = sm[255];
}

__global__ __launch_bounds__(512) void scan_bsum_kernel(int* __restrict__ bsum, int nb) {
    __shared__ int sm[512];
    int v = (threadIdx.x < nb) ? bsum[threadIdx.x] : 0;
    sm[threadIdx.x] = v;
    __syncthreads();
    for (int off = 1; off < 512; off <<= 1) {
        int t = (threadIdx.x >= off) ? sm[threadIdx.x - off] : 0;
        __syncthreads();
        sm[threadIdx.x] += t;
        __syncthreads();
    }
    if (threadIdx.x < nb) bsum[threadIdx.x] = sm[threadIdx.x] - v;
}

// add block offsets; init fill=ptr; zero raw (pre-seg_stage); set ptr[N]
__global__ __launch_bounds__(256) void scan_fix_kernel(int* __restrict__ ptr,
                                                       int* __restrict__ fill,
                                                       const int* __restrict__ bsum,
                                                       float* __restrict__ raw) {
    int idx = blockIdx.x * 256 + threadIdx.x;
    if (idx < N_NODES) {
        int p = ptr[idx] + bsum[blockIdx.x];
        ptr[idx] = p;
        fill[idx] = p;
        f32x4 z = (f32x4)(0.0f);
        f32x4* r4 = reinterpret_cast<f32x4*>(raw + (size_t)idx * H);
#pragma unroll
        for (int q = 0; q < 8; ++q) r4[q] = z;
    }
    if (idx == 0) ptr[N_NODES] = N_EDGES;
}

// scatter, 2 edges per thread for ILP (latency-bound kernel: double outstanding reqs)
__global__ __launch_bounds__(256) void scatter_big_kernel(const int* __restrict__ eidx,
                                                          const float* __restrict__ h_msg,
                                                          int* __restrict__ fill,
                                                          uint2* __restrict__ slotmap,
                                                          __half* __restrict__ hs) {
    int e0 = blockIdx.x * 512 + threadIdx.x;       // grid exact: N_EDGES/512
    int e1 = e0 + 256;
    int src0 = eidx[e0], src1 = eidx[e1];
    int dst0 = eidx[(size_t)N_EDGES + e0], dst1 = eidx[(size_t)N_EDGES + e1];
    int pos0 = atomicAdd(&fill[dst0], 1);
    int pos1 = atomicAdd(&fill[dst1], 1);
    float m0[H], m1[H];
    load_row32(h_msg + (size_t)e0 * H, m0);
    load_row32(h_msg + (size_t)e1 * H, m1);
    slotmap[pos0] = pack_eds(e0, dst0, src0);
    slotmap[pos1] = pack_eds(e1, dst1, src1);
    store_row32_h(reinterpret_cast<__half2*>(hs + (size_t)pos0 * H), m0);
    store_row32_h(reinterpret_cast<__half2*>(hs + (size_t)pos1 * H), m1);
}

__global__ __launch_bounds__(256) void seg_stage_big_kernel(const __half* __restrict__ hs,
                                                            const uint2* __restrict__ slotmap,
                                                            float* __restrict__ out) {
    __shared__ __half tile[256 * HSTRIDE];
    __shared__ int nid[256];
    int tid = threadIdx.x;
    int slot = blockIdx.x * 256 + tid;
    nid[tid] = unpack_dst(slotmap[slot]);
    const __half2* row = reinterpret_cast<const __half2*>(hs + (size_t)slot * H);  // sequential
    __half2* trow = reinterpret_cast<__half2*>(tile + tid * HSTRIDE);
#pragma unroll
    for (int q = 0; q < 16; ++q) trow[q] = row[q];
    __builtin_amdgcn_wave_barrier();               // wave-local scan: no block barrier
    seg_scan32_h(tile, nid, tid & ~31, tid & 31, out);
}

// ---------------- per-node: pre1 + nn MLP -> fp16 pernode[n][64]; re-zeros raw ----------------
__global__ __launch_bounds__(256) void pernode_kernel(const float* __restrict__ x,
                                                      float* __restrict__ raw,
                                                      const int* __restrict__ ptr,
                                                      const float* __restrict__ W_in,
                                                      const float* __restrict__ b_in,
                                                      const float* __restrict__ Wn1,
                                                      const float* __restrict__ bn1,
                                                      const float* __restrict__ Wn2,
                                                      const float* __restrict__ bn2,
                                                      const float* __restrict__ W2,
                                                      const float* __restrict__ c1,
                                                      const float* __restrict__ c0,
                                                      __half* __restrict__ pernode) {
    int i = blockIdx.x * blockDim.x + threadIdx.x;
    if (i >= N_NODES) return;
    float s[H], p1[H];
    __half2* row = reinterpret_cast<__half2*>(pernode + (size_t)i * 64);
    load_row32(raw + (size_t)i * H, s);
    {
        f32x4 z = (f32x4)(0.0f);
        f32x4* r4 = reinterpret_cast<f32x4*>(raw + (size_t)i * H);
#pragma unroll
        for (int q = 0; q < 8; ++q) r4[q] = z;
    }
    float deg = (float)(ptr[i + 1] - ptr[i]);
#pragma unroll
    for (int o = 0; o < H; ++o) p1[o] = fmaf(deg, c1[o], c0[o]);
    matvec32_acc(s, W2, p1);
    store_row32_h(row, p1);
    hnode_row(x, i, W_in, b_in, s);
    matvec32(s, Wn1, bn1, p1);
#pragma unroll
    for (int o = 0; o < H; ++o) p1[o] = lrelu(p1[o]);
    matvec32(p1, Wn2, bn2, s);
#pragma unroll
    for (int o = 0; o < H; ++o) s[o] = lrelu(s[o]);
    store_row32_h(row + 16, s);
}

// ---------------- fused pass2 (wave-local scan, no block barrier) ----------------
__global__ __launch_bounds__(256) void edge_fused_big_kernel(
    const __half* __restrict__ hs, const uint2* __restrict__ slotmap,
    const __half* __restrict__ pernode,
    const float* __restrict__ Wfold,
    const float* __restrict__ WN2, const float* __restrict__ bN2,
    const float* __restrict__ Wd, const float* __restrict__ bd,
    float* __restrict__ out_hmsg, float* __restrict__ out_ymsg,
    float* __restrict__ aggr_out) {
    __shared__ __half tile[256 * HSTRIDE];
    __shared__ int nid[256];
    int tid = threadIdx.x;
    int slot = blockIdx.x * 256 + tid;
    uint2 sm = slotmap[slot];                       // sequential 8B
    int e = unpack_e(sm), dst = unpack_dst(sm), src = unpack_src(sm);

    float m[H], t[H], u[H];
    const __half2* pn = reinterpret_cast<const __half2*>(pernode + (size_t)src * 64);

    load_row32_h(reinterpret_cast<const __half2*>(hs + (size_t)slot * H), m);  // sequential
    load_row32_h(pn, t);                            // remaining random gather
    matvec32_acc(m, Wfold, t);
#pragma unroll
    for (int o = 0; o < H; ++o) t[o] = lrelu(t[o]);

    matvec32(t, WN2, bN2, u);

    load_row32_h(pn + 16, t);
#pragma unroll
    for (int o = 0; o < H; ++o) m[o] = t[o] + lrelu(u[o]);

    store_row32(out_hmsg + (size_t)e * H, m);

    float z0 = bd[0], z1 = bd[1];
#pragma unroll
    for (int k = 0; k < H; ++k) {
        z0 = fmaf(m[k], Wd[k * 2 + 0], z0);
        z1 = fmaf(m[k], Wd[k * 2 + 1], z1);
    }
    float zm = fmaxf(z0, z1);
    float e0 = __expf(z0 - zm), e1 = __expf(z1 - zm);
    float inv = 1.0f / (e0 + e1);
    *reinterpret_cast<float2*>(out_ymsg + (size_t)e * 2) = make_float2(e0 * inv, e1 * inv);

    staged_segsum(m, dst, tid, tile, nid, aggr_out);
}

// ---------------- node update + beliefs ----------------
__global__ __launch_bounds__(256) void node_update_kernel(
    const float* __restrict__ x, const float* __restrict__ aggr_out,
    const float* __restrict__ W_in, const float* __restrict__ b_in,
    const float* __restrict__ WU, const float* __restrict__ bU,
    const float* __restrict__ Wb, const float* __restrict__ bb,
    float* __restrict__ out_beliefs) {
    int i = blockIdx.x * blockDim.x + threadIdx.x;
    if (i >= N_NODES) return;
    float a[H], t[H];
    hnode_row(x, i, W_in, b_in, a);
    matvec32(a, WU, bU, t);
    load_row32(aggr_out + (size_t)i * H, a);
    matvec32_acc(a, WU + H * H, t);
#pragma unroll
    for (int o = 0; o < H; ++o) t[o] = lrelu(t[o]);

    if (x[(size_t)i * 3] == 1.0f) {
        float z0 = bb[0], z1 = bb[1];
#pragma unroll
        for (int k = 0; k < H; ++k) {
            z0 = fmaf(t[k], Wb[k * 2 + 0], z0);
            z1 = fmaf(t[k], Wb[k * 2 + 1], z1);
        }
        float zm = fmaxf(z0, z1);
        float e0 = __expf(z0 - zm), e1 = __expf(z1 - zm);
        float inv = 1.0f / (e0 + e1);
        out_beliefs[(size_t)i * 2 + 0] = e0 * inv;
        out_beliefs[(size_t)i * 2 + 1] = e1 * inv;
    }
}

extern "C" void kernel_launch(void* const* d_in, const int* in_sizes, int n_in,
                              void* d_out, int out_size, void* d_ws, size_t ws_size,
                              hipStream_t stream) {
    const float* x     = (const float*)d_in[0];
    const int*   eidx  = (const int*)d_in[1];
    const float* h_msg = (const float*)d_in[2];
    const float* W_in = (const float*)d_in[3];  const float* b_in = (const float*)d_in[4];
    const float* We   = (const float*)d_in[5];  const float* be   = (const float*)d_in[6];
    const float* Wn1  = (const float*)d_in[7];  const float* bn1  = (const float*)d_in[8];
    const float* Wn2  = (const float*)d_in[9];  const float* bn2  = (const float*)d_in[10];
    const float* WN1  = (const float*)d_in[11]; const float* bN1  = (const float*)d_in[12];
    const float* WN2  = (const float*)d_in[13]; const float* bN2  = (const float*)d_in[14];
    const float* WU   = (const float*)d_in[15]; const float* bU   = (const float*)d_in[16];
    const float* Wd   = (const float*)d_in[17]; const float* bd   = (const float*)d_in[18];
    const float* Wb   = (const float*)d_in[19]; const float* bb   = (const float*)d_in[20];

    float* out         = (float*)d_out;
    float* out_hmsg    = out;
    float* out_ymsg    = out + (size_t)N_EDGES * H;
    float* out_beliefs = out + (size_t)N_EDGES * (H + 2);

    const int EB = N_EDGES / 256;                 // 12500 exact

    // workspace layout (~257 MB; round-10 proved ws >= 283 MB)
    char* w = (char*)d_ws;
    __half* pernode  = (__half*)w;   w += (size_t)N_NODES * 64 * sizeof(__half);  // 12.8 MB
    float*  raw      = (float*)w;    w += (size_t)N_NODES * H * sizeof(float);    // 12.8 MB
    uint2*  slotmap  = (uint2*)w;    w += (size_t)N_EDGES * sizeof(uint2);        // 25.6 MB
    __half* hs       = (__half*)w;   w += (size_t)N_EDGES * H * sizeof(__half);   // 204.8 MB
    float*  W2       = (float*)w;    w += 4096;
    float*  Wfold    = (float*)w;    w += 4096;
    float*  c1       = (float*)w;    w += 128;
    float*  c0       = (float*)w;    w += 128;
    int*    cnt      = (int*)w;      w += sizeof(int) * N_NODES;
    int*    ptr      = (int*)w;      w += sizeof(int) * (N_NODES + 1);
    int*    fill     = (int*)w;      w += sizeof(int) * N_NODES;
    int*    bsum     = (int*)w;

    fold_kernel<<<1, 1024, 0, stream>>>(We, be, WN1, bN1, W2, Wfold, c1, c0);

    zero_int_kernel<<<SCAN_BLOCKS, 256, 0, stream>>>(cnt, N_NODES);
    hist_kernel<<<EB, 256, 0, stream>>>(eidx, cnt);
    scan_block_kernel<<<SCAN_BLOCKS, 256, 0, stream>>>(cnt, ptr, bsum);
    scan_bsum_kernel<<<1, 512, 0, stream>>>(bsum, SCAN_BLOCKS);
    scan_fix_kernel<<<SCAN_BLOCKS, 256, 0, stream>>>(ptr, fill, bsum, raw);

    scatter_big_kernel<<<N_EDGES / 512, 256, 0, stream>>>(eidx, h_msg, fill, slotmap, hs);

    seg_stage_big_kernel<<<EB, 256, 0, stream>>>(hs, slotmap, raw);

    pernode_kernel<<<SCAN_BLOCKS, 256, 0, stream>>>(
        x, raw, ptr, W_in, b_in, Wn1, bn1, Wn2, bn2, W2, c1, c0, pernode);

    edge_fused_big_kernel<<<EB, 256, 0, stream>>>(
        hs, slotmap, pernode, Wfold, WN2, bN2, Wd, bd,
        out_hmsg, out_ymsg, raw);

    node_update_kernel<<<SCAN_BLOCKS, 256, 0, stream>>>(
        x, raw, W_in, b_in, WU, bU, Wb, bb, out_beliefs);
}